// Round 2
// baseline (1563.509 us; speedup 1.0000x reference)
//
#include <hip/hip_runtime.h>

// Problem: B=16, N=128, C=256, H=8, D=32.  All I/O fp32.
#define SCALE 0.17677669529663687f   // 1/sqrt(32)

typedef __attribute__((ext_vector_type(8))) __bf16 bf16x8;
typedef __attribute__((ext_vector_type(8))) unsigned short u16x8;
typedef __attribute__((ext_vector_type(4))) float f32x4;

__device__ inline float bf2f(unsigned short s) {
    union { unsigned int u; float f; } x; x.u = ((unsigned int)s) << 16; return x.f;
}
__device__ inline unsigned short f2bf(float f) {
    union { float f; unsigned int u; } x; x.f = f;
    return (unsigned short)((x.u + 0x7fffu + ((x.u >> 16) & 1u)) >> 16);   // RTNE
}
__device__ inline u16x8 cvt8(float4 a, float4 b) {
    u16x8 p;
    p[0] = f2bf(a.x); p[1] = f2bf(a.y); p[2] = f2bf(a.z); p[3] = f2bf(a.w);
    p[4] = f2bf(b.x); p[5] = f2bf(b.y); p[6] = f2bf(b.z); p[7] = f2bf(b.w);
    return p;
}
// swizzled offsets (u16 units). 8-chunk rows (64 ch):
__device__ inline int offT(int row, int c8) { return row * 64 + ((c8 ^ row) & 7) * 8; }
// 32-chunk rows (attn, 256 ch): swizzle low 3 bits of chunk index only
__device__ inline int offAttn(int j, int c8) { return j * 256 + (((c8) & 24) | ((c8 ^ j) & 7)) * 8; }

// ---- prep: convert We/Woe f32 -> bf16, pre-arranged in swizzled k-tile layout ----
__global__ void __launch_bounds__(256) prep_kernel(
    const float* __restrict__ We, const float* __restrict__ Woe,
    unsigned short* __restrict__ pWe, unsigned short* __restrict__ pWoe)
{
    const int id = blockIdx.x * 256 + threadIdx.x;        // 0..16383
    const float* W = (id & 8192) ? Woe : We;
    unsigned short* P = (id & 8192) ? pWoe : pWe;
    const int rem = id & 8191;
    const int kt = rem >> 11, chunk = rem & 2047, row = chunk >> 3, c8 = chunk & 7;
    const float* s = W + row * 256 + kt * 64 + c8 * 8;
    *(u16x8*)(P + kt * 16384 + offT(row, c8)) = cvt8(*(const float4*)s, *(const float4*)(s + 4));
}

// ---- qkv: {q,k,v} = node @ W^T + b  via MFMA.  grid (16, 6) ----
__global__ void __launch_bounds__(256) qkv_kernel(
    const float* __restrict__ node,
    const float* __restrict__ Wq, const float* __restrict__ bq,
    const float* __restrict__ Wk, const float* __restrict__ bk,
    const float* __restrict__ Wv, const float* __restrict__ bv,
    float* __restrict__ qs, float* __restrict__ kf, float* __restrict__ vf)
{
    __shared__ __align__(16) unsigned short As[128 * 64], Bs[128 * 64];
    const int wsel = blockIdx.y >> 1;                 // 0=q 1=k 2=v
    const int halfn = (blockIdx.y & 1) * 128;         // output-channel half
    const float* W    = wsel == 0 ? Wq : (wsel == 1 ? Wk : Wv);
    const float* bias = wsel == 0 ? bq : (wsel == 1 ? bk : bv);
    float*       out  = wsel == 0 ? qs : (wsel == 1 ? kf : vf);
    const float scl = wsel == 0 ? SCALE : 1.0f;
    const int tid = threadIdx.x, lane = tid & 63, wid = tid >> 6;
    const int wM = (wid >> 1) * 64, wN = (wid & 1) * 64;
    const int fr = lane & 15, quad = lane >> 4;
    const size_t M0 = (size_t)blockIdx.x * 128;

    f32x4 acc[4][4];
#pragma unroll
    for (int i = 0; i < 4; ++i)
#pragma unroll
        for (int j = 0; j < 4; ++j) acc[i][j] = (f32x4){0.f, 0.f, 0.f, 0.f};

    for (int kt = 0; kt < 4; ++kt) {
        __syncthreads();
#pragma unroll
        for (int i = 0; i < 4; ++i) {
            const int c = tid + i * 256, row = c >> 3, c8 = c & 7;
            const float* sa = node + (M0 + row) * 256 + kt * 64 + c8 * 8;
            const float* sb = W + (size_t)(halfn + row) * 256 + kt * 64 + c8 * 8;
            *(u16x8*)(As + offT(row, c8)) = cvt8(*(const float4*)sa, *(const float4*)(sa + 4));
            *(u16x8*)(Bs + offT(row, c8)) = cvt8(*(const float4*)sb, *(const float4*)(sb + 4));
        }
        __syncthreads();
#pragma unroll
        for (int ks = 0; ks < 2; ++ks) {
            bf16x8 af[4], bb[4];
#pragma unroll
            for (int mb = 0; mb < 4; ++mb) {
                const int row = wM + mb * 16 + fr;
                af[mb] = *(const bf16x8*)(As + offT(row, ks * 4 + quad));
            }
#pragma unroll
            for (int nb = 0; nb < 4; ++nb) {
                const int row = wN + nb * 16 + fr;
                bb[nb] = *(const bf16x8*)(Bs + offT(row, ks * 4 + quad));
            }
#pragma unroll
            for (int mb = 0; mb < 4; ++mb)
#pragma unroll
                for (int nb = 0; nb < 4; ++nb)
                    acc[mb][nb] = __builtin_amdgcn_mfma_f32_16x16x32_bf16(af[mb], bb[nb], acc[mb][nb], 0, 0, 0);
        }
    }
#pragma unroll
    for (int nb = 0; nb < 4; ++nb) {
        const int gc = halfn + wN + nb * 16 + fr;
        const float bv_ = bias[gc];
#pragma unroll
        for (int mb = 0; mb < 4; ++mb)
#pragma unroll
            for (int r = 0; r < 4; ++r) {
                const int j = wM + mb * 16 + quad * 4 + r;
                out[(M0 + j) * 256 + gc] = (acc[mb][nb][r] + bv_) * scl;
            }
    }
}

// ---- won: out_node = agg @ Won^T + bon.  grid (16, 2) ----
__global__ void __launch_bounds__(256) won_kernel(
    const float* __restrict__ agg, const float* __restrict__ Won,
    const float* __restrict__ bon, float* __restrict__ out_node)
{
    __shared__ __align__(16) unsigned short As[128 * 64], Bs[128 * 64];
    const int halfn = blockIdx.y * 128;
    const int tid = threadIdx.x, lane = tid & 63, wid = tid >> 6;
    const int wM = (wid >> 1) * 64, wN = (wid & 1) * 64;
    const int fr = lane & 15, quad = lane >> 4;
    const size_t M0 = (size_t)blockIdx.x * 128;

    f32x4 acc[4][4];
#pragma unroll
    for (int i = 0; i < 4; ++i)
#pragma unroll
        for (int j = 0; j < 4; ++j) acc[i][j] = (f32x4){0.f, 0.f, 0.f, 0.f};

    for (int kt = 0; kt < 4; ++kt) {
        __syncthreads();
#pragma unroll
        for (int i = 0; i < 4; ++i) {
            const int c = tid + i * 256, row = c >> 3, c8 = c & 7;
            const float* sa = agg + (M0 + row) * 256 + kt * 64 + c8 * 8;
            const float* sb = Won + (size_t)(halfn + row) * 256 + kt * 64 + c8 * 8;
            *(u16x8*)(As + offT(row, c8)) = cvt8(*(const float4*)sa, *(const float4*)(sa + 4));
            *(u16x8*)(Bs + offT(row, c8)) = cvt8(*(const float4*)sb, *(const float4*)(sb + 4));
        }
        __syncthreads();
#pragma unroll
        for (int ks = 0; ks < 2; ++ks) {
            bf16x8 af[4], bb[4];
#pragma unroll
            for (int mb = 0; mb < 4; ++mb)
                af[mb] = *(const bf16x8*)(As + offT(wM + mb * 16 + fr, ks * 4 + quad));
#pragma unroll
            for (int nb = 0; nb < 4; ++nb)
                bb[nb] = *(const bf16x8*)(Bs + offT(wN + nb * 16 + fr, ks * 4 + quad));
#pragma unroll
            for (int mb = 0; mb < 4; ++mb)
#pragma unroll
                for (int nb = 0; nb < 4; ++nb)
                    acc[mb][nb] = __builtin_amdgcn_mfma_f32_16x16x32_bf16(af[mb], bb[nb], acc[mb][nb], 0, 0, 0);
        }
    }
#pragma unroll
    for (int nb = 0; nb < 4; ++nb) {
        const int gc = halfn + wN + nb * 16 + fr;
        const float bv_ = bon[gc];
#pragma unroll
        for (int mb = 0; mb < 4; ++mb)
#pragma unroll
            for (int r = 0; r < 4; ++r) {
                const int j = wM + mb * 16 + quad * 4 + r;
                out_node[(M0 + j) * 256 + gc] = acc[mb][nb][r] + bv_;
            }
    }
}

// ---- fused: per (b,i), processed in TWO j-halves of 64 rows each ----
// Per half: stage edge rows (offT, reg-prefetched) -> GEMM1 64x256x256 ->
// gated write into 32KB attn buffer -> GEMM2 -> online-softmax partial
// (per-thread running m/l/av with flash-style rescale across halves).
// LDS: attn 32K | As 8K (aliased by 6K final-reduction scratch) = 40K
// -> 3 blocks/CU (24 waves) vs previous 2 blocks (16 waves).
__global__ void __launch_bounds__(512, 6) fused_kernel(
    const float* __restrict__ edge,
    const unsigned short* __restrict__ pWe,  const float* __restrict__ be,
    const unsigned short* __restrict__ pWoe, const float* __restrict__ boe,
    const float* __restrict__ qs, const float* __restrict__ kf, const float* __restrict__ vf,
    float* __restrict__ aggout, float* __restrict__ out_edge)
{
    extern __shared__ __align__(16) char smem[];
    unsigned short* attn_s = (unsigned short*)smem;            // 32768 B: 64 rows x 256 ch
    unsigned short* As     = (unsigned short*)(smem + 32768);  // 8192 B staging
    float*          sred   = (float*)(smem + 32768);           // 6144 B final scratch (aliases As)

    const int mtile = blockIdx.x;                 // b*128 + i
    const int tid = threadIdx.x, lane = tid & 63, wid = tid >> 6;
    const int wM = (wid >> 2) * 32;               // j rows within half (2 blocks of 32)
    const int wN = (wid & 3) * 64;                // channels (4 blocks of 64)
    const int fr = lane & 15, quad = lane >> 4;
    const size_t rowA0 = (size_t)mtile * 128;
    const int b128 = (mtile >> 7) * 128;

    const int srow = tid >> 3, sc8 = tid & 7;     // staging: 64 rows x 8 chunks
    float4 pa, pb;                                // register prefetch (proven pattern)
    {
        const float* s = edge + (rowA0 + srow) * 256 + sc8 * 8;
        pa = *(const float4*)s; pb = *(const float4*)(s + 4);
    }

    // per-thread online-softmax state (phase 3); each thread owns 32 rows x 1 ch per half
    const int c = tid & 255, sub = tid >> 8;
    const int cc8 = c >> 3, ccl = c & 7;
    float m_t = -1e30f, l_t = 0.f, av_t = 0.f;

    const float* qrow = qs + (size_t)mtile * 256;

    for (int h = 0; h < 2; ++h) {
        // ---------- GEMM1: e = edge[h*64..h*64+64) @ We^T ----------
        f32x4 acc[2][4];
#pragma unroll
        for (int i = 0; i < 2; ++i)
#pragma unroll
            for (int j = 0; j < 4; ++j) acc[i][j] = (f32x4){0.f, 0.f, 0.f, 0.f};

        for (int kt = 0; kt < 4; ++kt) {
            __syncthreads();                       // As free (prev MFMA / prev-half phase3 done)
            *(u16x8*)(As + offT(srow, sc8)) = cvt8(pa, pb);
            __syncthreads();                       // As visible
            if (kt < 3 || h == 0) {                // prefetch next staging tile
                const int nh = (kt < 3) ? h : 1, nkt = (kt + 1) & 3;
                const float* s = edge + (rowA0 + nh * 64 + srow) * 256 + nkt * 64 + sc8 * 8;
                pa = *(const float4*)s; pb = *(const float4*)(s + 4);
            }
            const unsigned short* BW = pWe + kt * 16384;
#pragma unroll
            for (int ks = 0; ks < 2; ++ks) {
                bf16x8 af[2], bb[4];
#pragma unroll
                for (int mb = 0; mb < 2; ++mb)
                    af[mb] = *(const bf16x8*)(As + offT(wM + mb * 16 + fr, ks * 4 + quad));
#pragma unroll
                for (int nb = 0; nb < 4; ++nb)
                    bb[nb] = *(const bf16x8*)(BW + offT(wN + nb * 16 + fr, ks * 4 + quad));
#pragma unroll
                for (int mb = 0; mb < 2; ++mb)
#pragma unroll
                    for (int nb = 0; nb < 4; ++nb)
                        acc[mb][nb] = __builtin_amdgcn_mfma_f32_16x16x32_bf16(af[mb], bb[nb], acc[mb][nb], 0, 0, 0);
            }
        }

        {   // ---------- gated epilogue -> attn_s (rows local to half) ----------
#pragma unroll
            for (int nb = 0; nb < 4; ++nb) {
                const int gc = wN + nb * 16 + fr;
                const float qv = qrow[gc], bev = be[gc];
                const int c8 = gc >> 3, cl = gc & 7;
#pragma unroll
                for (int mb = 0; mb < 2; ++mb)
#pragma unroll
                    for (int r = 0; r < 4; ++r) {
                        const int j = wM + mb * 16 + quad * 4 + r;     // 0..63
                        const float e = acc[mb][nb][r] + bev;
                        const float kv = kf[(size_t)(b128 + h * 64 + j) * 256 + gc];
                        attn_s[offAttn(j, c8) + cl] = f2bf(qv * kv * (e + 1.0f) * e);
                    }
            }
        }
        __syncthreads();                           // attn half complete

        // ---------- GEMM2: out_edge rows = attn @ Woe^T + boe ----------
        f32x4 acc2[2][4];
#pragma unroll
        for (int i = 0; i < 2; ++i)
#pragma unroll
            for (int j = 0; j < 4; ++j) acc2[i][j] = (f32x4){0.f, 0.f, 0.f, 0.f};

#pragma unroll
        for (int kt = 0; kt < 4; ++kt) {
            const unsigned short* BW = pWoe + kt * 16384;
#pragma unroll
            for (int ks = 0; ks < 2; ++ks) {
                bf16x8 af[2], bb[4];
#pragma unroll
                for (int mb = 0; mb < 2; ++mb)
                    af[mb] = *(const bf16x8*)(attn_s + offAttn(wM + mb * 16 + fr, kt * 8 + ks * 4 + quad));
#pragma unroll
                for (int nb = 0; nb < 4; ++nb)
                    bb[nb] = *(const bf16x8*)(BW + offT(wN + nb * 16 + fr, ks * 4 + quad));
#pragma unroll
                for (int mb = 0; mb < 2; ++mb)
#pragma unroll
                    for (int nb = 0; nb < 4; ++nb)
                        acc2[mb][nb] = __builtin_amdgcn_mfma_f32_16x16x32_bf16(af[mb], bb[nb], acc2[mb][nb], 0, 0, 0);
            }
        }
#pragma unroll
        for (int nb = 0; nb < 4; ++nb) {
            const int gc = wN + nb * 16 + fr;
            const float bo = boe[gc];
#pragma unroll
            for (int mb = 0; mb < 2; ++mb)
#pragma unroll
                for (int r = 0; r < 4; ++r) {
                    const int j = wM + mb * 16 + quad * 4 + r;
                    out_edge[((size_t)mtile * 128 + h * 64 + j) * 256 + gc] = acc2[mb][nb][r] + bo;
                }
        }

        // ---------- phase 3 partial: online softmax over this half's 64 rows ----------
        {
            float mh = -1e30f;
#pragma unroll 8
            for (int j2 = 0; j2 < 32; ++j2)
                mh = fmaxf(mh, bf2f(attn_s[offAttn(sub * 32 + j2, cc8) + ccl]));
            const float newm = fmaxf(m_t, mh);
            const float scale = __expf(m_t - newm);    // 0 on first half (m_t = -1e30)
            l_t *= scale; av_t *= scale; m_t = newm;
#pragma unroll 4
            for (int j2 = 0; j2 < 32; ++j2) {
                const int j = sub * 32 + j2;
                const float w = __expf(bf2f(attn_s[offAttn(j, cc8) + ccl]) - m_t);
                l_t += w;
                av_t += w * vf[(size_t)(b128 + h * 64 + j) * 256 + c];
            }
        }
        // next half's kt-loop barriers order these attn reads before the next gate write
    }

    // ---------- final cross-sub combine (sred aliases As; As is long dead) ----------
    float* sm  = sred;          // [512]
    float* sl  = sred + 512;    // [512]
    float* sav = sred + 1024;   // [512]
    sm[tid] = m_t; sl[tid] = l_t; sav[tid] = av_t;
    __syncthreads();
    if (tid < 256) {
        const float m0 = sm[tid], m1 = sm[tid + 256];
        const float M = fmaxf(m0, m1);
        const float s0 = __expf(m0 - M), s1 = __expf(m1 - M);
        const float L  = sl[tid] * s0 + sl[tid + 256] * s1;
        const float AV = sav[tid] * s0 + sav[tid + 256] * s1;
        aggout[(size_t)mtile * 256 + tid] = AV / L;
    }
}

extern "C" void kernel_launch(void* const* d_in, const int* in_sizes, int n_in,
                              void* d_out, int out_size, void* d_ws, size_t ws_size,
                              hipStream_t stream) {
    const float* node = (const float*)d_in[0];
    const float* edge = (const float*)d_in[1];
    const float* Wq   = (const float*)d_in[2];
    const float* bq   = (const float*)d_in[3];
    const float* Wk   = (const float*)d_in[4];
    const float* bk   = (const float*)d_in[5];
    const float* Wv   = (const float*)d_in[6];
    const float* bv   = (const float*)d_in[7];
    const float* We   = (const float*)d_in[8];
    const float* be   = (const float*)d_in[9];
    const float* Woe  = (const float*)d_in[10];
    const float* boe  = (const float*)d_in[11];
    const float* Won  = (const float*)d_in[12];
    const float* bon  = (const float*)d_in[13];

    float* out_node = (float*)d_out;                      // [2048][256]
    float* out_edge = out_node + (size_t)2048 * 256;      // [262144][256]

    // ws: pWe 128K | pWoe 128K | qs(/agg) 2M | kf 2M | vf 2M  = 6.5 MB
    char* ws = (char*)d_ws;
    unsigned short* pWe  = (unsigned short*)ws;
    unsigned short* pWoe = (unsigned short*)(ws + 131072);
    float* qs = (float*)(ws + 262144);
    float* kf = qs + (size_t)2048 * 256;
    float* vf = kf + (size_t)2048 * 256;
    float* agg = qs;                                      // qs dead after fused gates

    static const int lds_bytes = 40960;                   // 32K attn + 8K As/sred
    hipFuncSetAttribute((const void*)fused_kernel,
                        hipFuncAttributeMaxDynamicSharedMemorySize, lds_bytes);

    hipLaunchKernelGGL(prep_kernel, dim3(64), dim3(256), 0, stream, We, Woe, pWe, pWoe);
    hipLaunchKernelGGL(qkv_kernel, dim3(16, 6), dim3(256), 0, stream,
                       node, Wq, bq, Wk, bk, Wv, bv, qs, kf, vf);
    hipLaunchKernelGGL(fused_kernel, dim3(2048), dim3(512), lds_bytes, stream,
                       edge, pWe, be, pWoe, boe, qs, kf, vf, agg, out_edge);
    hipLaunchKernelGGL(won_kernel, dim3(16, 2), dim3(256), 0, stream,
                       agg, Won, bon, out_node);
}